// Round 2
// baseline (244.735 us; speedup 1.0000x reference)
//
#include <hip/hip_runtime.h>
#include <hip/hip_bf16.h>

// Problem constants (B=1, H=W=64, C=768, nh=12, hd=64)
#define S_TOK 4096
#define CDIM  768
#define N3C   2304
#define NH    12
#define HD    64

#define LOG2E 1.44269504f

typedef __attribute__((ext_vector_type(8))) short short8;
typedef __attribute__((ext_vector_type(4))) short short4v;
typedef __attribute__((ext_vector_type(4))) float float4v;
typedef __attribute__((ext_vector_type(4))) unsigned uint4v;

__device__ __forceinline__ float b2f(short s) {
    return __uint_as_float(((unsigned)(unsigned short)s) << 16);
}
__device__ __forceinline__ short f2b(float f) {   // round-to-nearest-even
    unsigned u = __float_as_uint(f);
    unsigned r = (u + 0x7FFFu + ((u >> 16) & 1u)) >> 16;
    return (short)r;
}

#if __has_builtin(__builtin_amdgcn_exp2f)
#define EXP2F __builtin_amdgcn_exp2f
#else
#define EXP2F exp2f
#endif

// pack trunc-bf16(a) into low short, trunc-bf16(b) into high short
__device__ __forceinline__ unsigned pack_trunc(float a, float b) {
    return __builtin_amdgcn_perm(__float_as_uint(b), __float_as_uint(a), 0x07060302u);
}

__device__ __forceinline__ short8 u4_to_s8(unsigned a, unsigned b, unsigned c, unsigned d) {
    union { uint4v u; short8 s; } t;
    t.u = (uint4v){a, b, c, d};
    return t.s;
}

// async global->LDS DMA, 16B per lane, dest = ldsbase + lane*16 (linear)
__device__ __forceinline__ void load_lds16(const void* g, void* l) {
    __builtin_amdgcn_global_load_lds(
        (const __attribute__((address_space(1))) unsigned int*)g,
        (__attribute__((address_space(3))) unsigned int*)l, 16, 0, 0);
}

// ---------------------------------------------------------------------------
// Elementwise fp32 -> bf16 cast (4 elems/thread)
// ---------------------------------------------------------------------------
__global__ __launch_bounds__(256) void cast_bf16_kernel(
    const float* __restrict__ in, short* __restrict__ out, int n4)
{
    int i = blockIdx.x * 256 + threadIdx.x;
    if (i >= n4) return;
    float4 v = ((const float4*)in)[i];
    short4v o4 = { f2b(v.x), f2b(v.y), f2b(v.z), f2b(v.w) };
    *(short4v*)&out[(size_t)i * 4] = o4;
}

// ---------------------------------------------------------------------------
// Transpose + cast: in fp32 [R][C] -> out bf16 [C][R]. 64x64 tiles, 256 thr.
// ---------------------------------------------------------------------------
__global__ __launch_bounds__(256) void transpose_cast_kernel(
    const float* __restrict__ in, short* __restrict__ out, int R, int C)
{
    __shared__ float t[64][65];
    const int tid = threadIdx.x;
    const int c0 = blockIdx.x * 64, r0 = blockIdx.y * 64;
    const int li = tid >> 6;      // 0..3
    const int lj = tid & 63;
#pragma unroll
    for (int p = 0; p < 16; ++p) {
        int i = p * 4 + li;
        t[i][lj] = in[(size_t)(r0 + i) * C + c0 + lj];
    }
    __syncthreads();
#pragma unroll
    for (int p = 0; p < 16; ++p) {
        int i = p * 4 + li;
        out[(size_t)(c0 + i) * R + r0 + lj] = f2b(t[lj][i]);
    }
}

// ---------------------------------------------------------------------------
// MFMA GEMM core: C[128x128] = A[128xK] @ Bt[128xK]^T
// ---------------------------------------------------------------------------
#define GEMM_CORE(A_, Bt_)                                                     \
    __shared__ __align__(16) short a_s[128][72];                               \
    __shared__ __align__(16) short b_s[128][72];                               \
    const int tid  = threadIdx.x;                                              \
    const int m0 = blockIdx.y * 128;                                           \
    const int n0 = blockIdx.x * 128;                                           \
    const int lane = tid & 63, w = tid >> 6;                                   \
    const int l15 = lane & 15, quad = lane >> 4;                               \
    const int wr = w >> 1, wc = w & 1;                                         \
    const int srow = tid >> 1;                                                 \
    const int scol = (tid & 1) * 32;                                           \
    float4v acc[4][4];                                                         \
    _Pragma("unroll")                                                          \
    for (int i = 0; i < 4; ++i)                                                \
        _Pragma("unroll")                                                      \
        for (int j = 0; j < 4; ++j) acc[i][j] = (float4v){0.f,0.f,0.f,0.f};    \
    for (int k0 = 0; k0 < 768; k0 += 64) {                                     \
        __syncthreads();                                                       \
        const short* ga = A_ + (size_t)(m0 + srow) * 768 + k0 + scol;          \
        const short* gb = Bt_ + (size_t)(n0 + srow) * 768 + k0 + scol;         \
        _Pragma("unroll")                                                      \
        for (int v = 0; v < 4; ++v) {                                          \
            *(uint4*)&a_s[srow][scol + v*8] = *(const uint4*)(ga + v*8);       \
            *(uint4*)&b_s[srow][scol + v*8] = *(const uint4*)(gb + v*8);       \
        }                                                                      \
        __syncthreads();                                                       \
        _Pragma("unroll")                                                      \
        for (int kk = 0; kk < 64; kk += 32) {                                  \
            short8 af[4], bfr[4];                                              \
            _Pragma("unroll")                                                  \
            for (int i = 0; i < 4; ++i)                                        \
                af[i] = *(const short8*)&a_s[wr*64 + i*16 + l15][kk + quad*8]; \
            _Pragma("unroll")                                                  \
            for (int j = 0; j < 4; ++j)                                        \
                bfr[j] = *(const short8*)&b_s[wc*64 + j*16 + l15][kk + quad*8];\
            _Pragma("unroll")                                                  \
            for (int i = 0; i < 4; ++i)                                        \
                _Pragma("unroll")                                              \
                for (int j = 0; j < 4; ++j)                                    \
                    acc[i][j] = __builtin_amdgcn_mfma_f32_16x16x32_bf16(       \
                        af[i], bfr[j], acc[i][j], 0, 0, 0);                    \
        }                                                                      \
    }

// QKV GEMM: writes Qb[head][s][d], Kb[head][s][d], Vt[head][d][s] (bf16)
__global__ __launch_bounds__(256) void gemm_qkv_mfma(
    const short* __restrict__ A, const short* __restrict__ Bt,
    const float* __restrict__ bias,
    short* __restrict__ Qb, short* __restrict__ Kb, short* __restrict__ Vt)
{
    GEMM_CORE(A, Bt)

    const int sec = n0 / CDIM;      // tile fully inside one of q/k/v
    float bj[4];
#pragma unroll
    for (int j = 0; j < 4; ++j) bj[j] = bias[n0 + wc*64 + j*16 + l15];

    if (sec < 2) {
        short* dst = (sec == 0) ? Qb : Kb;
#pragma unroll
        for (int i = 0; i < 4; ++i)
#pragma unroll
            for (int j = 0; j < 4; ++j) {
                const int nn = (n0 + wc*64 + j*16 + l15) % CDIM;
                const int head = nn >> 6, d = nn & 63;
#pragma unroll
                for (int r = 0; r < 4; ++r) {
                    const int s = m0 + wr*64 + i*16 + quad*4 + r;
                    dst[((size_t)head * S_TOK + s) * HD + d] = f2b(acc[i][j][r] + bj[j]);
                }
            }
    } else {
#pragma unroll
        for (int i = 0; i < 4; ++i)
#pragma unroll
            for (int j = 0; j < 4; ++j) {
                const int nn = (n0 + wc*64 + j*16 + l15) % CDIM;
                const int head = nn >> 6, d = nn & 63;
                const int sbase = m0 + wr*64 + i*16 + quad*4;
                short4v v4;
#pragma unroll
                for (int r = 0; r < 4; ++r) v4[r] = f2b(acc[i][j][r] + bj[j]);
                *(short4v*)&Vt[((size_t)head * HD + d) * S_TOK + sbase] = v4;
            }
    }
}

// Proj GEMM: out fp32 [4096][768] = A @ Bt^T + bias
__global__ __launch_bounds__(256) void gemm_proj_mfma(
    const short* __restrict__ A, const short* __restrict__ Bt,
    const float* __restrict__ bias, float* __restrict__ out)
{
    GEMM_CORE(A, Bt)

    float bj[4];
#pragma unroll
    for (int j = 0; j < 4; ++j) bj[j] = bias[n0 + wc*64 + j*16 + l15];

#pragma unroll
    for (int i = 0; i < 4; ++i)
#pragma unroll
        for (int j = 0; j < 4; ++j) {
            const int n = n0 + wc*64 + j*16 + l15;
#pragma unroll
            for (int r = 0; r < 4; ++r) {
                const int s = m0 + wr*64 + i*16 + quad*4 + r;
                out[(size_t)s * CDIM + n] = acc[i][j][r] + bj[j];
            }
        }
}

// ---------------------------------------------------------------------------
// Rel-pos tables via MFMA. One block per (y, head); 64 queries s0=y*64..+63.
// Outputs are PRE-SCALED by log2e (flash computes softmax in exp2 domain).
// ---------------------------------------------------------------------------
__global__ __launch_bounds__(256) void rel_mfma_kernel(
    const short* __restrict__ Qb, const float* __restrict__ rph,
    const float* __restrict__ rpw, short* __restrict__ Relh,
    short* __restrict__ Relw)
{
    __shared__ __align__(16) short q_s [64][72];
    __shared__ __align__(16) short rh_s[64][72];
    __shared__ __align__(16) short rw_s[128][72];

    const int tid  = threadIdx.x;
    const int y    = blockIdx.x;
    const int head = blockIdx.y;
    const int s0   = y * 64;
    const int w = tid >> 6, lane = tid & 63;
    const int l15 = lane & 15, quad = lane >> 4;
    const int srow = tid >> 2;            // 0..63
    const int scol = (tid & 3) << 4;      // 0,16,32,48

    // ---- stage Q (bf16 passthrough) ----
    {
        const uint4* g = (const uint4*)(Qb + ((size_t)head * S_TOK + s0 + srow) * HD + scol);
        *(uint4*)&q_s[srow][scol]     = g[0];
        *(uint4*)&q_s[srow][scol + 8] = g[1];
    }
    // ---- stage rph rows y..y+63 (fp32 -> bf16) ----
    {
        const float* g = rph + (size_t)(y + srow) * HD + scol;
        short tmp[16];
#pragma unroll
        for (int i = 0; i < 16; i += 4) {
            float4 v = *(const float4*)(g + i);
            tmp[i] = f2b(v.x); tmp[i+1] = f2b(v.y); tmp[i+2] = f2b(v.z); tmp[i+3] = f2b(v.w);
        }
        *(short8*)&rh_s[srow][scol]     = *(short8*)&tmp[0];
        *(short8*)&rh_s[srow][scol + 8] = *(short8*)&tmp[8];
    }
    // ---- stage rpw rows 0..127 (row 127 clamped; never consumed) ----
#pragma unroll
    for (int half = 0; half < 2; ++half) {
        const int row = srow + half * 64;
        const int rr  = row > 126 ? 126 : row;
        const float* g = rpw + (size_t)rr * HD + scol;
        short tmp[16];
#pragma unroll
        for (int i = 0; i < 16; i += 4) {
            float4 v = *(const float4*)(g + i);
            tmp[i] = f2b(v.x); tmp[i+1] = f2b(v.y); tmp[i+2] = f2b(v.z); tmp[i+3] = f2b(v.w);
        }
        *(short8*)&rw_s[row][scol]     = *(short8*)&tmp[0];
        *(short8*)&rw_s[row][scol + 8] = *(short8*)&tmp[8];
    }
    __syncthreads();

    const short8 qa0 = *(const short8*)&q_s[w * 16 + l15][quad * 8];
    const short8 qa1 = *(const short8*)&q_s[w * 16 + l15][32 + quad * 8];

    // ---- relh: RH col j = y+jj, ky = 63-jj ----
#pragma unroll
    for (int ct = 0; ct < 4; ++ct) {
        const int jj = ct * 16 + l15;
        short8 b0 = *(const short8*)&rh_s[jj][quad * 8];
        short8 b1 = *(const short8*)&rh_s[jj][32 + quad * 8];
        float4v z = (float4v){0.f, 0.f, 0.f, 0.f};
        z = __builtin_amdgcn_mfma_f32_16x16x32_bf16(qa0, b0, z, 0, 0, 0);
        z = __builtin_amdgcn_mfma_f32_16x16x32_bf16(qa1, b1, z, 0, 0, 0);
        const int ky = 63 - jj;
#pragma unroll
        for (int r = 0; r < 4; ++r) {
            const int q = w * 16 + quad * 4 + r;
            Relh[((size_t)head * S_TOK + s0 + q) * HD + ky] = f2b(z[r] * LOG2E);
        }
    }

    // ---- relw: kx = q+63-j, keep 0<=kx<64 ----
#pragma unroll
    for (int ct = 0; ct < 8; ++ct) {
        const int j = ct * 16 + l15;
        short8 b0 = *(const short8*)&rw_s[j][quad * 8];
        short8 b1 = *(const short8*)&rw_s[j][32 + quad * 8];
        float4v z = (float4v){0.f, 0.f, 0.f, 0.f};
        z = __builtin_amdgcn_mfma_f32_16x16x32_bf16(qa0, b0, z, 0, 0, 0);
        z = __builtin_amdgcn_mfma_f32_16x16x32_bf16(qa1, b1, z, 0, 0, 0);
#pragma unroll
        for (int r = 0; r < 4; ++r) {
            const int q  = w * 16 + quad * 4 + r;
            const int kx = q + 63 - j;
            if (kx >= 0 && kx < 64)
                Relw[((size_t)head * S_TOK + s0 + q) * HD + kx] = f2b(z[r] * LOG2E);
        }
    }
}

// ---------------------------------------------------------------------------
// Flash attention v4: 128-thread blocks, 2 waves x 32 queries each.
//   K/V A-frags are wave-independent -> reading them once per wave and using
//   them for TWO q-tiles halves per-query LDS read traffic vs v3 (4 waves).
//   Staging via global_load_lds (async DMA, linear dest): LDS rows unpadded
//   [64][64]; column slots XOR-swizzled (slot' = slot ^ (row&7)) with the
//   inverse swizzle + K key bit-permutation folded into the per-lane GLOBAL
//   source address (rule: linear dest + pre-swizzled source + swizzled read).
//   Key permutation (unchanged from v3): LDS row j holds key
//     key(j) = (j&3) | ((j>>4)&1)<<2 | ((j>>2)&3)<<3 | (j&32)
//   so S^T tile kt's outputs are the lane's own PV B-frag keys (no P LDS).
// ---------------------------------------------------------------------------
__global__ __launch_bounds__(128, 2) void flash_kernel(
    const short* __restrict__ Qb, const short* __restrict__ Kb,
    const short* __restrict__ Vt, const short* __restrict__ Relh,
    const short* __restrict__ Relw, short* __restrict__ attn_b)
{
    __shared__ __align__(16) short k_s [2][64][64];   // [buf][perm key][d]   (swizzled cols)
    __shared__ __align__(16) short vt_s[2][64][64];   // [buf][d][key]        (swizzled cols)

    const int tid  = threadIdx.x;
    const int head = blockIdx.y;
    const int s0   = blockIdx.x * 64;
    const int w    = tid >> 6, lane = tid & 63;
    const int l15  = lane & 15, quad = lane >> 4;

    const float C1 = 0.125f * LOG2E;

    // ---- staging source mapping (per-lane, chunk-invariant) ----
    const int lj = lane >> 3;            // row within 8-row DMA group
    const int sl = (lane & 7) ^ lj;      // logical 16B slot this lane must fetch
    // K: key for (w, ii=0, lj) under the row bit-permutation
    const int kf = (lj & 3) + ((lj & 4) << 1) + w * 32;
    const short* pK = Kb + (size_t)head * S_TOK * HD + (size_t)kf * HD + sl * 8;
    // V: d-row for (w, ii=0, lj); keys advance along S
    const short* pV = Vt + ((size_t)head * HD + w * 32 + lj) * S_TOK + sl * 8;

    // ---- LDS read column byte-offsets (swizzled; row&7 == l15&7 for all tiles) ----
    const int roff0 = (quad ^ (l15 & 7)) << 4;   // logical slot quad   (d/keys 0..31)
    const int roff1 = roff0 ^ 64;                // logical slot 4+quad (d/keys 32..63)

    // ---- Q B-frags: 2 q-tiles (32 queries per wave) ----
    short8 qb[2][2];
#pragma unroll
    for (int qt = 0; qt < 2; ++qt) {
        const short* qrow = Qb + ((size_t)head * S_TOK + s0 + w * 32 + qt * 16 + l15) * HD;
        qb[qt][0] = *(const short8*)(qrow + quad * 8);
        qb[qt][1] = *(const short8*)(qrow + 32 + quad * 8);
    }

    // ---- relw invariants: rw[qt][kt][r], key = kbase(kt) + quad*8 + r ----
    float rwv[2][4][4];
#pragma unroll
    for (int qt = 0; qt < 2; ++qt) {
        const short* rwrow = Relw + ((size_t)head * S_TOK + s0 + w * 32 + qt * 16 + l15) * HD;
#pragma unroll
        for (int kt = 0; kt < 4; ++kt) {
            const int base = ((kt & 1) << 2) | ((kt >> 1) << 5);
            short4v v = *(const short4v*)(rwrow + base + quad * 8);
#pragma unroll
            for (int r = 0; r < 4; ++r) rwv[qt][kt][r] = b2f(v[r]);
        }
    }

    const short* rhrow0 = Relh + ((size_t)head * S_TOK + s0 + w * 32 + l15) * HD;
    const short* rhrow1 = rhrow0 + (size_t)16 * HD;
    float rhc0 = b2f(rhrow0[0]);
    float rhc1 = b2f(rhrow1[0]);

    // ones A-frag for the denominator
    short8 aones;
#pragma unroll
    for (int j = 0; j < 8; ++j) aones[j] = (short)0x3F80;

    float4v od[2][4];
#pragma unroll
    for (int qt = 0; qt < 2; ++qt)
#pragma unroll
        for (int dt = 0; dt < 4; ++dt) od[qt][dt] = (float4v){0.f, 0.f, 0.f, 0.f};
    float4v dq0 = (float4v){0.f, 0.f, 0.f, 0.f};
    float4v dq1 = (float4v){0.f, 0.f, 0.f, 0.f};

    // ---- prologue: DMA chunk 0 into buf 0 ----
    {
        short* lk = &k_s[0][w * 32][0];
        short* lv = &vt_s[0][w * 32][0];
        load_lds16(pK,        lk);             // ii=0: keys kf+{0}
        load_lds16(pK + 1024, lk + 8  * 64);   // ii=1: keys +16
        load_lds16(pK + 256,  lk + 16 * 64);   // ii=2: keys +4
        load_lds16(pK + 1280, lk + 24 * 64);   // ii=3: keys +20
        load_lds16(pV,                      lv);
        load_lds16(pV + 8  * S_TOK,         lv + 8  * 64);
        load_lds16(pV + 16 * S_TOK,         lv + 16 * 64);
        load_lds16(pV + 24 * S_TOK,         lv + 24 * 64);
    }
    __syncthreads();

    for (int ic = 0; ic < 64; ++ic) {
        const int cur = ic & 1;

        // ---- issue next-chunk DMA into the other buffer ----
        short rhn0, rhn1;
        if (ic < 63) {
            const short* gk = pK + (ic + 1) * (64 * HD);
            const short* gv = pV + (ic + 1) * 64;
            short* lk = &k_s[cur ^ 1][w * 32][0];
            short* lv = &vt_s[cur ^ 1][w * 32][0];
            load_lds16(gk,        lk);
            load_lds16(gk + 1024, lk + 8  * 64);
            load_lds16(gk + 256,  lk + 16 * 64);
            load_lds16(gk + 1280, lk + 24 * 64);
            load_lds16(gv,              lv);
            load_lds16(gv + 8  * S_TOK, lv + 8  * 64);
            load_lds16(gv + 16 * S_TOK, lv + 16 * 64);
            load_lds16(gv + 24 * S_TOK, lv + 24 * 64);
            rhn0 = rhrow0[ic + 1];
            rhn1 = rhrow1[ic + 1];
        }

        // ---- S^T per key-tile: K-frags read once, used by both q-tiles ----
        unsigned pkk[2][8];
#pragma unroll
        for (int kt = 0; kt < 4; ++kt) {
            const char* krp = (const char*)&k_s[cur][kt * 16 + l15][0];
            const short8 ka0 = *(const short8*)(krp + roff0);
            const short8 ka1 = *(const short8*)(krp + roff1);
            {
                float4v z = (float4v){0.f, 0.f, 0.f, 0.f};
                z = __builtin_amdgcn_mfma_f32_16x16x32_bf16(ka0, qb[0][0], z, 0, 0, 0);
                z = __builtin_amdgcn_mfma_f32_16x16x32_bf16(ka1, qb[0][1], z, 0, 0, 0);
                float p0 = EXP2F(C1 * z[0] + (rhc0 + rwv[0][kt][0]));
                float p1 = EXP2F(C1 * z[1] + (rhc0 + rwv[0][kt][1]));
                float p2 = EXP2F(C1 * z[2] + (rhc0 + rwv[0][kt][2]));
                float p3 = EXP2F(C1 * z[3] + (rhc0 + rwv[0][kt][3]));
                pkk[0][kt * 2]     = pack_trunc(p0, p1);
                pkk[0][kt * 2 + 1] = pack_trunc(p2, p3);
            }
            {
                float4v z = (float4v){0.f, 0.f, 0.f, 0.f};
                z = __builtin_amdgcn_mfma_f32_16x16x32_bf16(ka0, qb[1][0], z, 0, 0, 0);
                z = __builtin_amdgcn_mfma_f32_16x16x32_bf16(ka1, qb[1][1], z, 0, 0, 0);
                float p0 = EXP2F(C1 * z[0] + (rhc1 + rwv[1][kt][0]));
                float p1 = EXP2F(C1 * z[1] + (rhc1 + rwv[1][kt][1]));
                float p2 = EXP2F(C1 * z[2] + (rhc1 + rwv[1][kt][2]));
                float p3 = EXP2F(C1 * z[3] + (rhc1 + rwv[1][kt][3]));
                pkk[1][kt * 2]     = pack_trunc(p0, p1);
                pkk[1][kt * 2 + 1] = pack_trunc(p2, p3);
            }
        }
        const short8 pb00 = u4_to_s8(pkk[0][0], pkk[0][1], pkk[0][2], pkk[0][3]);
        const short8 pb01 = u4_to_s8(pkk[0][4], pkk[0][5], pkk[0][6], pkk[0][7]);
        const short8 pb10 = u4_to_s8(pkk[1][0], pkk[1][1], pkk[1][2], pkk[1][3]);
        const short8 pb11 = u4_to_s8(pkk[1][4], pkk[1][5], pkk[1][6], pkk[1][7]);

        // ---- PV: V-frags read once, used by both q-tiles ----
#pragma unroll
        for (int dt = 0; dt < 4; ++dt) {
            const char* vrp = (const char*)&vt_s[cur][dt * 16 + l15][0];
            const short8 va0 = *(const short8*)(vrp + roff0);
            const short8 va1 = *(const short8*)(vrp + roff1);
            od[0][dt] = __builtin_amdgcn_mfma_f32_16x16x32_bf16(va0, pb00, od[0][dt], 0, 0, 0);
            od[0][dt] = __builtin_amdgcn_mfma_f32_16x16x32_bf16(va1, pb01, od[0][dt], 0, 0, 0);
            od[1][dt] = __builtin_amdgcn_mfma_f32_16x16x32_bf16(va0, pb10, od[1][dt], 0, 0, 0);
            od[1][dt] = __builtin_amdgcn_mfma_f32_16x16x32_bf16(va1, pb11, od[1][dt], 0, 0, 0);
        }
        dq0 = __builtin_amdgcn_mfma_f32_16x16x32_bf16(aones, pb00, dq0, 0, 0, 0);
        dq0 = __builtin_amdgcn_mfma_f32_16x16x32_bf16(aones, pb01, dq0, 0, 0, 0);
        dq1 = __builtin_amdgcn_mfma_f32_16x16x32_bf16(aones, pb10, dq1, 0, 0, 0);
        dq1 = __builtin_amdgcn_mfma_f32_16x16x32_bf16(aones, pb11, dq1, 0, 0, 0);

        if (ic < 63) {
            rhc0 = b2f(rhn0);
            rhc1 = b2f(rhn1);
            __syncthreads();   // drains vmcnt: DMA of buf^1 complete, reads of cur done
        }
    }

    // ---- epilogue: denominator rows equal -> scalar inv; b64 stores ----
#pragma unroll
    for (int qt = 0; qt < 2; ++qt) {
        const float inv = 1.f / ((qt == 0) ? dq0[0] : dq1[0]);
        short* outp = attn_b + (size_t)(s0 + w * 32 + qt * 16 + l15) * CDIM + head * HD;
#pragma unroll
        for (int dt = 0; dt < 4; ++dt) {
            short4v o4;
#pragma unroll
            for (int r = 0; r < 4; ++r) o4[r] = f2b(od[qt][dt][r] * inv);
            *(short4v*)(outp + dt * 16 + quad * 4) = o4;
        }
    }
}

// ---------------------------------------------------------------------------
extern "C" void kernel_launch(void* const* d_in, const int* in_sizes, int n_in,
                              void* d_out, int out_size, void* d_ws, size_t ws_size,
                              hipStream_t stream)
{
    const float* x    = (const float*)d_in[0];
    const float* qkvw = (const float*)d_in[1];
    const float* qkvb = (const float*)d_in[2];
    const float* rph  = (const float*)d_in[3];
    const float* rpw  = (const float*)d_in[4];
    const float* pw   = (const float*)d_in[5];
    const float* pb   = (const float*)d_in[6];
    float* out = (float*)d_out;

    // ws layout (shorts), total ~48.8 MB
    const size_t HSD = (size_t)NH * S_TOK * HD;   // 3,145,728
    short* xb     = (short*)d_ws;                 // 4096*768
    short* wt     = xb + (size_t)S_TOK * CDIM;    // 2304*768 (qkv_w^T)
    short* pwt    = wt + (size_t)N3C * CDIM;      // 768*768  (proj_w^T)
    short* Qb     = pwt + (size_t)CDIM * CDIM;
    short* Kb     = Qb + HSD;
    short* Vt     = Kb + HSD;
    short* Relh   = Vt + HSD;
    short* Relw   = Relh + HSD;
    short* attn_b = Relw + HSD;                   // 4096*768

    cast_bf16_kernel<<<S_TOK * CDIM / 4 / 256, 256, 0, stream>>>(x, xb, S_TOK * CDIM / 4);
    transpose_cast_kernel<<<dim3(N3C / 64, CDIM / 64), 256, 0, stream>>>(qkvw, wt, CDIM, N3C);
    transpose_cast_kernel<<<dim3(CDIM / 64, CDIM / 64), 256, 0, stream>>>(pw, pwt, CDIM, CDIM);

    gemm_qkv_mfma<<<dim3(N3C / 128, S_TOK / 128), 256, 0, stream>>>(
        xb, wt, qkvb, Qb, Kb, Vt);
    rel_mfma_kernel<<<dim3(64, NH), 256, 0, stream>>>(Qb, rph, rpw, Relh, Relw);
    flash_kernel<<<dim3(64, NH), 128, 0, stream>>>(Qb, Kb, Vt, Relh, Relw, attn_b);
    gemm_proj_mfma<<<dim3(CDIM / 128, S_TOK / 128), 256, 0, stream>>>(
        attn_b, pwt, pb, out);
}

// Round 3
// 224.197 us; speedup vs baseline: 1.0916x; 1.0916x over previous
//
#include <hip/hip_runtime.h>
#include <hip/hip_bf16.h>

// Problem constants (B=1, H=W=64, C=768, nh=12, hd=64)
#define S_TOK 4096
#define CDIM  768
#define N3C   2304
#define NH    12
#define HD    64

#define LOG2E 1.44269504f

typedef __attribute__((ext_vector_type(8))) short short8;
typedef __attribute__((ext_vector_type(4))) short short4v;
typedef __attribute__((ext_vector_type(4))) float float4v;
typedef __attribute__((ext_vector_type(4))) unsigned uint4v;

__device__ __forceinline__ float b2f(short s) {
    return __uint_as_float(((unsigned)(unsigned short)s) << 16);
}
__device__ __forceinline__ short f2b(float f) {   // round-to-nearest-even
    unsigned u = __float_as_uint(f);
    unsigned r = (u + 0x7FFFu + ((u >> 16) & 1u)) >> 16;
    return (short)r;
}

#if __has_builtin(__builtin_amdgcn_exp2f)
#define EXP2F __builtin_amdgcn_exp2f
#else
#define EXP2F exp2f
#endif

// pack trunc-bf16(a) into low short, trunc-bf16(b) into high short
__device__ __forceinline__ unsigned pack_trunc(float a, float b) {
    return __builtin_amdgcn_perm(__float_as_uint(b), __float_as_uint(a), 0x07060302u);
}

__device__ __forceinline__ short8 u4_to_s8(unsigned a, unsigned b, unsigned c, unsigned d) {
    union { uint4v u; short8 s; } t;
    t.u = (uint4v){a, b, c, d};
    return t.s;
}

// async global->LDS DMA, 16B per lane, dest = ldsbase + lane*16 (linear)
__device__ __forceinline__ void load_lds16(const void* g, void* l) {
    __builtin_amdgcn_global_load_lds(
        (const __attribute__((address_space(1))) unsigned int*)g,
        (__attribute__((address_space(3))) unsigned int*)l, 16, 0, 0);
}

// ---------------------------------------------------------------------------
// Elementwise fp32 -> bf16 cast (4 elems/thread)
// ---------------------------------------------------------------------------
__global__ __launch_bounds__(256) void cast_bf16_kernel(
    const float* __restrict__ in, short* __restrict__ out, int n4)
{
    int i = blockIdx.x * 256 + threadIdx.x;
    if (i >= n4) return;
    float4 v = ((const float4*)in)[i];
    short4v o4 = { f2b(v.x), f2b(v.y), f2b(v.z), f2b(v.w) };
    *(short4v*)&out[(size_t)i * 4] = o4;
}

// ---------------------------------------------------------------------------
// Transpose + cast: in fp32 [R][C] -> out bf16 [C][R]. 64x64 tiles, 256 thr.
// ---------------------------------------------------------------------------
__global__ __launch_bounds__(256) void transpose_cast_kernel(
    const float* __restrict__ in, short* __restrict__ out, int R, int C)
{
    __shared__ float t[64][65];
    const int tid = threadIdx.x;
    const int c0 = blockIdx.x * 64, r0 = blockIdx.y * 64;
    const int li = tid >> 6;      // 0..3
    const int lj = tid & 63;
#pragma unroll
    for (int p = 0; p < 16; ++p) {
        int i = p * 4 + li;
        t[i][lj] = in[(size_t)(r0 + i) * C + c0 + lj];
    }
    __syncthreads();
#pragma unroll
    for (int p = 0; p < 16; ++p) {
        int i = p * 4 + li;
        out[(size_t)(c0 + i) * R + r0 + lj] = f2b(t[lj][i]);
    }
}

// ---------------------------------------------------------------------------
// MFMA GEMM core: C[128x128] = A[128xK] @ Bt[128xK]^T
// ---------------------------------------------------------------------------
#define GEMM_CORE(A_, Bt_)                                                     \
    __shared__ __align__(16) short a_s[128][72];                               \
    __shared__ __align__(16) short b_s[128][72];                               \
    const int tid  = threadIdx.x;                                              \
    const int m0 = blockIdx.y * 128;                                           \
    const int n0 = blockIdx.x * 128;                                           \
    const int lane = tid & 63, w = tid >> 6;                                   \
    const int l15 = lane & 15, quad = lane >> 4;                               \
    const int wr = w >> 1, wc = w & 1;                                         \
    const int srow = tid >> 1;                                                 \
    const int scol = (tid & 1) * 32;                                           \
    float4v acc[4][4];                                                         \
    _Pragma("unroll")                                                          \
    for (int i = 0; i < 4; ++i)                                                \
        _Pragma("unroll")                                                      \
        for (int j = 0; j < 4; ++j) acc[i][j] = (float4v){0.f,0.f,0.f,0.f};    \
    for (int k0 = 0; k0 < 768; k0 += 64) {                                     \
        __syncthreads();                                                       \
        const short* ga = A_ + (size_t)(m0 + srow) * 768 + k0 + scol;          \
        const short* gb = Bt_ + (size_t)(n0 + srow) * 768 + k0 + scol;         \
        _Pragma("unroll")                                                      \
        for (int v = 0; v < 4; ++v) {                                          \
            *(uint4*)&a_s[srow][scol + v*8] = *(const uint4*)(ga + v*8);       \
            *(uint4*)&b_s[srow][scol + v*8] = *(const uint4*)(gb + v*8);       \
        }                                                                      \
        __syncthreads();                                                       \
        _Pragma("unroll")                                                      \
        for (int kk = 0; kk < 64; kk += 32) {                                  \
            short8 af[4], bfr[4];                                              \
            _Pragma("unroll")                                                  \
            for (int i = 0; i < 4; ++i)                                        \
                af[i] = *(const short8*)&a_s[wr*64 + i*16 + l15][kk + quad*8]; \
            _Pragma("unroll")                                                  \
            for (int j = 0; j < 4; ++j)                                        \
                bfr[j] = *(const short8*)&b_s[wc*64 + j*16 + l15][kk + quad*8];\
            _Pragma("unroll")                                                  \
            for (int i = 0; i < 4; ++i)                                        \
                _Pragma("unroll")                                              \
                for (int j = 0; j < 4; ++j)                                    \
                    acc[i][j] = __builtin_amdgcn_mfma_f32_16x16x32_bf16(       \
                        af[i], bfr[j], acc[i][j], 0, 0, 0);                    \
        }                                                                      \
    }

// QKV GEMM: writes Qb[head][s][d], Kb[head][s][d], Vt[head][d][s] (bf16)
__global__ __launch_bounds__(256) void gemm_qkv_mfma(
    const short* __restrict__ A, const short* __restrict__ Bt,
    const float* __restrict__ bias,
    short* __restrict__ Qb, short* __restrict__ Kb, short* __restrict__ Vt)
{
    GEMM_CORE(A, Bt)

    const int sec = n0 / CDIM;      // tile fully inside one of q/k/v
    float bj[4];
#pragma unroll
    for (int j = 0; j < 4; ++j) bj[j] = bias[n0 + wc*64 + j*16 + l15];

    if (sec < 2) {
        short* dst = (sec == 0) ? Qb : Kb;
#pragma unroll
        for (int i = 0; i < 4; ++i)
#pragma unroll
            for (int j = 0; j < 4; ++j) {
                const int nn = (n0 + wc*64 + j*16 + l15) % CDIM;
                const int head = nn >> 6, d = nn & 63;
#pragma unroll
                for (int r = 0; r < 4; ++r) {
                    const int s = m0 + wr*64 + i*16 + quad*4 + r;
                    dst[((size_t)head * S_TOK + s) * HD + d] = f2b(acc[i][j][r] + bj[j]);
                }
            }
    } else {
#pragma unroll
        for (int i = 0; i < 4; ++i)
#pragma unroll
            for (int j = 0; j < 4; ++j) {
                const int nn = (n0 + wc*64 + j*16 + l15) % CDIM;
                const int head = nn >> 6, d = nn & 63;
                const int sbase = m0 + wr*64 + i*16 + quad*4;
                short4v v4;
#pragma unroll
                for (int r = 0; r < 4; ++r) v4[r] = f2b(acc[i][j][r] + bj[j]);
                *(short4v*)&Vt[((size_t)head * HD + d) * S_TOK + sbase] = v4;
            }
    }
}

// Proj GEMM: out fp32 [4096][768] = A @ Bt^T + bias
__global__ __launch_bounds__(256) void gemm_proj_mfma(
    const short* __restrict__ A, const short* __restrict__ Bt,
    const float* __restrict__ bias, float* __restrict__ out)
{
    GEMM_CORE(A, Bt)

    float bj[4];
#pragma unroll
    for (int j = 0; j < 4; ++j) bj[j] = bias[n0 + wc*64 + j*16 + l15];

#pragma unroll
    for (int i = 0; i < 4; ++i)
#pragma unroll
        for (int j = 0; j < 4; ++j) {
            const int n = n0 + wc*64 + j*16 + l15;
#pragma unroll
            for (int r = 0; r < 4; ++r) {
                const int s = m0 + wr*64 + i*16 + quad*4 + r;
                out[(size_t)s * CDIM + n] = acc[i][j][r] + bj[j];
            }
        }
}

// ---------------------------------------------------------------------------
// Rel-pos tables via MFMA. One block per (y, head); 64 queries s0=y*64..+63.
// Outputs are PRE-SCALED by log2e (flash computes softmax in exp2 domain).
// ---------------------------------------------------------------------------
__global__ __launch_bounds__(256) void rel_mfma_kernel(
    const short* __restrict__ Qb, const float* __restrict__ rph,
    const float* __restrict__ rpw, short* __restrict__ Relh,
    short* __restrict__ Relw)
{
    __shared__ __align__(16) short q_s [64][72];
    __shared__ __align__(16) short rh_s[64][72];
    __shared__ __align__(16) short rw_s[128][72];

    const int tid  = threadIdx.x;
    const int y    = blockIdx.x;
    const int head = blockIdx.y;
    const int s0   = y * 64;
    const int w = tid >> 6, lane = tid & 63;
    const int l15 = lane & 15, quad = lane >> 4;
    const int srow = tid >> 2;            // 0..63
    const int scol = (tid & 3) << 4;      // 0,16,32,48

    // ---- stage Q (bf16 passthrough) ----
    {
        const uint4* g = (const uint4*)(Qb + ((size_t)head * S_TOK + s0 + srow) * HD + scol);
        *(uint4*)&q_s[srow][scol]     = g[0];
        *(uint4*)&q_s[srow][scol + 8] = g[1];
    }
    // ---- stage rph rows y..y+63 (fp32 -> bf16) ----
    {
        const float* g = rph + (size_t)(y + srow) * HD + scol;
        short tmp[16];
#pragma unroll
        for (int i = 0; i < 16; i += 4) {
            float4 v = *(const float4*)(g + i);
            tmp[i] = f2b(v.x); tmp[i+1] = f2b(v.y); tmp[i+2] = f2b(v.z); tmp[i+3] = f2b(v.w);
        }
        *(short8*)&rh_s[srow][scol]     = *(short8*)&tmp[0];
        *(short8*)&rh_s[srow][scol + 8] = *(short8*)&tmp[8];
    }
    // ---- stage rpw rows 0..127 (row 127 clamped; never consumed) ----
#pragma unroll
    for (int half = 0; half < 2; ++half) {
        const int row = srow + half * 64;
        const int rr  = row > 126 ? 126 : row;
        const float* g = rpw + (size_t)rr * HD + scol;
        short tmp[16];
#pragma unroll
        for (int i = 0; i < 16; i += 4) {
            float4 v = *(const float4*)(g + i);
            tmp[i] = f2b(v.x); tmp[i+1] = f2b(v.y); tmp[i+2] = f2b(v.z); tmp[i+3] = f2b(v.w);
        }
        *(short8*)&rw_s[row][scol]     = *(short8*)&tmp[0];
        *(short8*)&rw_s[row][scol + 8] = *(short8*)&tmp[8];
    }
    __syncthreads();

    const short8 qa0 = *(const short8*)&q_s[w * 16 + l15][quad * 8];
    const short8 qa1 = *(const short8*)&q_s[w * 16 + l15][32 + quad * 8];

    // ---- relh: RH col j = y+jj, ky = 63-jj ----
#pragma unroll
    for (int ct = 0; ct < 4; ++ct) {
        const int jj = ct * 16 + l15;
        short8 b0 = *(const short8*)&rh_s[jj][quad * 8];
        short8 b1 = *(const short8*)&rh_s[jj][32 + quad * 8];
        float4v z = (float4v){0.f, 0.f, 0.f, 0.f};
        z = __builtin_amdgcn_mfma_f32_16x16x32_bf16(qa0, b0, z, 0, 0, 0);
        z = __builtin_amdgcn_mfma_f32_16x16x32_bf16(qa1, b1, z, 0, 0, 0);
        const int ky = 63 - jj;
#pragma unroll
        for (int r = 0; r < 4; ++r) {
            const int q = w * 16 + quad * 4 + r;
            Relh[((size_t)head * S_TOK + s0 + q) * HD + ky] = f2b(z[r] * LOG2E);
        }
    }

    // ---- relw: kx = q+63-j, keep 0<=kx<64 ----
#pragma unroll
    for (int ct = 0; ct < 8; ++ct) {
        const int j = ct * 16 + l15;
        short8 b0 = *(const short8*)&rw_s[j][quad * 8];
        short8 b1 = *(const short8*)&rw_s[j][32 + quad * 8];
        float4v z = (float4v){0.f, 0.f, 0.f, 0.f};
        z = __builtin_amdgcn_mfma_f32_16x16x32_bf16(qa0, b0, z, 0, 0, 0);
        z = __builtin_amdgcn_mfma_f32_16x16x32_bf16(qa1, b1, z, 0, 0, 0);
#pragma unroll
        for (int r = 0; r < 4; ++r) {
            const int q  = w * 16 + quad * 4 + r;
            const int kx = q + 63 - j;
            if (kx >= 0 && kx < 64)
                Relw[((size_t)head * S_TOK + s0 + q) * HD + kx] = f2b(z[r] * LOG2E);
        }
    }
}

// ---------------------------------------------------------------------------
// Flash attention v6: pair-split over key chunks, 256 threads / 4 waves.
//   Lesson from v4 (2-wave): halving LDS traffic while dropping to 1.5
//   waves/SIMD REGRESSED (latency-bound). v6 keeps 12 waves/CU *and* the
//   sharing: waves {0,1} (ph=0) process key chunks 0..31, waves {2,3} (ph=1)
//   chunks 32..63; within a pair each wave owns 32 queries (qh). K/V frags
//   are thus read by only 2 waves per chunk. Partial (od, dq) are combined
//   across pairs through LDS at the end.
//   Staging via global_load_lds (linear dest, pre-swizzled source, swizzled
//   read -> zero bank conflicts, verified in v4). K double-buffered per pair,
//   V single-buffered per pair (2 barriers per chunk-step; 64 total = v3).
//   Key bit-permutation (v3): LDS row j holds key
//     key(j) = (j&3) | ((j>>4)&1)<<2 | ((j>>2)&3)<<3 | (j&32)
//   so S^T tile kt's outputs are the lane's own PV B-frag keys (no P LDS).
// ---------------------------------------------------------------------------
__global__ __launch_bounds__(256, 3) void flash_kernel(
    const short* __restrict__ Qb, const short* __restrict__ Kb,
    const short* __restrict__ Vt, const short* __restrict__ Relh,
    const short* __restrict__ Relw, short* __restrict__ attn_b)
{
    // shorts 0..16383: K[pair][buf][64][64]; 16384..24575: V[pair][64][64]
    __shared__ __align__(16) short lds_s[24576];

    const int tid  = threadIdx.x;
    const int head = blockIdx.y;
    const int s0   = blockIdx.x * 64;
    const int w    = tid >> 6, lane = tid & 63;
    const int l15  = lane & 15, quad = lane >> 4;
    const int ph   = w >> 1;          // key-chunk half: chunks ph*32 + t
    const int qh   = w & 1;           // query half: queries qh*32 + ...

    const float C1 = 0.125f * LOG2E;

    // ---- staging lane mapping (linear dest, pre-swizzled source) ----
    const int lj = lane >> 3;             // row within 8-row DMA group
    const int sl = (lane & 7) ^ lj;       // logical 16B slot this lane fetches
    const int kf0 = (lj & 3) + ((lj & 4) << 1) + qh * 32;  // permuted key, ii=0

    const short* pKs = Kb + (size_t)head * S_TOK * HD
                     + (size_t)(ph * 32 * 64 + kf0) * HD + sl * 8;
    const short* pVs = Vt + ((size_t)head * HD + qh * 32 + lj) * S_TOK
                     + ph * 32 * 64 + sl * 8;

    // wave-uniform LDS dest bases
    short* lk0 = &lds_s[(ph * 2 + 0) << 12] + qh * 32 * 64;
    short* lk1 = &lds_s[(ph * 2 + 1) << 12] + qh * 32 * 64;
    short* lv  = &lds_s[16384 + (ph << 12)] + qh * 32 * 64;
    const short* krd0 = &lds_s[(ph * 2 + 0) << 12];
    const short* krd1 = &lds_s[(ph * 2 + 1) << 12];
    const short* vrd  = &lds_s[16384 + (ph << 12)];

    // swizzled read byte-offsets (row&7 == l15&7 for all frag rows)
    const int roff0 = (quad ^ (l15 & 7)) << 4;   // logical slot quad
    const int roff1 = roff0 ^ 64;                // logical slot 4+quad

    // ---- Q B-frags: 2 q-tiles (32 queries per wave) ----
    short8 qb[2][2];
#pragma unroll
    for (int qt = 0; qt < 2; ++qt) {
        const short* qrow = Qb + ((size_t)head * S_TOK + s0 + qh * 32 + qt * 16 + l15) * HD;
        qb[qt][0] = *(const short8*)(qrow + quad * 8);
        qb[qt][1] = *(const short8*)(qrow + 32 + quad * 8);
    }

    // ---- relw invariants: rwv[qt][kt][r], key = kbase(kt) + quad*8 + r ----
    float rwv[2][4][4];
#pragma unroll
    for (int qt = 0; qt < 2; ++qt) {
        const short* rwrow = Relw + ((size_t)head * S_TOK + s0 + qh * 32 + qt * 16 + l15) * HD;
#pragma unroll
        for (int kt = 0; kt < 4; ++kt) {
            const int base = ((kt & 1) << 2) | ((kt >> 1) << 5);
            short4v v = *(const short4v*)(rwrow + base + quad * 8);
#pragma unroll
            for (int r = 0; r < 4; ++r) rwv[qt][kt][r] = b2f(v[r]);
        }
    }

    const short* rhrow0 = Relh + ((size_t)head * S_TOK + s0 + qh * 32 + l15) * HD;
    const short* rhrow1 = rhrow0 + 16 * HD;

    // ones A-frag for the denominator
    short8 aones;
#pragma unroll
    for (int j = 0; j < 8; ++j) aones[j] = (short)0x3F80;

    float4v od[2][4];
#pragma unroll
    for (int qt = 0; qt < 2; ++qt)
#pragma unroll
        for (int dt = 0; dt < 4; ++dt) od[qt][dt] = (float4v){0.f, 0.f, 0.f, 0.f};
    float4v dq0 = (float4v){0.f, 0.f, 0.f, 0.f};
    float4v dq1 = (float4v){0.f, 0.f, 0.f, 0.f};

    // ---- prologue: DMA K chunk (ph*32) into buf0 ----
    load_lds16(pKs,        lk0);
    load_lds16(pKs + 1024, lk0 + 8  * 64);
    load_lds16(pKs + 256,  lk0 + 16 * 64);
    load_lds16(pKs + 1280, lk0 + 24 * 64);
    __syncthreads();

    for (int t = 0; t < 32; ++t) {
        const int cur = t & 1;
        const short* krd = cur ? krd1 : krd0;
        short* lkn = cur ? lk0 : lk1;

        // ---- V-DMA current chunk (prev PV separated by loop-end barrier) ----
        load_lds16(pVs,               lv);
        load_lds16(pVs + 8  * S_TOK,  lv + 8  * 64);
        load_lds16(pVs + 16 * S_TOK,  lv + 16 * 64);
        load_lds16(pVs + 24 * S_TOK,  lv + 24 * 64);
        // ---- K-DMA next chunk into the other buffer ----
        if (t < 31) {
            const short* pk = pKs + 4096;
            load_lds16(pk,        lkn);
            load_lds16(pk + 1024, lkn + 8  * 64);
            load_lds16(pk + 256,  lkn + 16 * 64);
            load_lds16(pk + 1280, lkn + 24 * 64);
        }
        pKs += 4096;
        pVs += 64;

        const int c = ph * 32 + t;
        const float rhc0 = b2f(rhrow0[c]);
        const float rhc1 = b2f(rhrow1[c]);

        // ---- S-phase: K frags read once, used by both q-tiles ----
        unsigned pkk[2][8];
#pragma unroll
        for (int kt = 0; kt < 4; ++kt) {
            const char* krp = (const char*)(krd + (kt * 16 + l15) * 64);
            const short8 ka0 = *(const short8*)(krp + roff0);
            const short8 ka1 = *(const short8*)(krp + roff1);
            {
                float4v z = (float4v){0.f, 0.f, 0.f, 0.f};
                z = __builtin_amdgcn_mfma_f32_16x16x32_bf16(ka0, qb[0][0], z, 0, 0, 0);
                z = __builtin_amdgcn_mfma_f32_16x16x32_bf16(ka1, qb[0][1], z, 0, 0, 0);
                float p0 = EXP2F(C1 * z[0] + (rhc0 + rwv[0][kt][0]));
                float p1 = EXP2F(C1 * z[1] + (rhc0 + rwv[0][kt][1]));
                float p2 = EXP2F(C1 * z[2] + (rhc0 + rwv[0][kt][2]));
                float p3 = EXP2F(C1 * z[3] + (rhc0 + rwv[0][kt][3]));
                pkk[0][kt * 2]     = pack_trunc(p0, p1);
                pkk[0][kt * 2 + 1] = pack_trunc(p2, p3);
            }
            {
                float4v z = (float4v){0.f, 0.f, 0.f, 0.f};
                z = __builtin_amdgcn_mfma_f32_16x16x32_bf16(ka0, qb[1][0], z, 0, 0, 0);
                z = __builtin_amdgcn_mfma_f32_16x16x32_bf16(ka1, qb[1][1], z, 0, 0, 0);
                float p0 = EXP2F(C1 * z[0] + (rhc1 + rwv[1][kt][0]));
                float p1 = EXP2F(C1 * z[1] + (rhc1 + rwv[1][kt][1]));
                float p2 = EXP2F(C1 * z[2] + (rhc1 + rwv[1][kt][2]));
                float p3 = EXP2F(C1 * z[3] + (rhc1 + rwv[1][kt][3]));
                pkk[1][kt * 2]     = pack_trunc(p0, p1);
                pkk[1][kt * 2 + 1] = pack_trunc(p2, p3);
            }
        }
        const short8 pb00 = u4_to_s8(pkk[0][0], pkk[0][1], pkk[0][2], pkk[0][3]);
        const short8 pb01 = u4_to_s8(pkk[0][4], pkk[0][5], pkk[0][6], pkk[0][7]);
        const short8 pb10 = u4_to_s8(pkk[1][0], pkk[1][1], pkk[1][2], pkk[1][3]);
        const short8 pb11 = u4_to_s8(pkk[1][4], pkk[1][5], pkk[1][6], pkk[1][7]);

        __syncthreads();   // drains vmcnt: V (and next K) landed; K reads done

        // ---- PV: V frags read once, used by both q-tiles ----
#pragma unroll
        for (int dt = 0; dt < 4; ++dt) {
            const char* vrp = (const char*)(vrd + (dt * 16 + l15) * 64);
            const short8 va0 = *(const short8*)(vrp + roff0);
            const short8 va1 = *(const short8*)(vrp + roff1);
            od[0][dt] = __builtin_amdgcn_mfma_f32_16x16x32_bf16(va0, pb00, od[0][dt], 0, 0, 0);
            od[0][dt] = __builtin_amdgcn_mfma_f32_16x16x32_bf16(va1, pb01, od[0][dt], 0, 0, 0);
            od[1][dt] = __builtin_amdgcn_mfma_f32_16x16x32_bf16(va0, pb10, od[1][dt], 0, 0, 0);
            od[1][dt] = __builtin_amdgcn_mfma_f32_16x16x32_bf16(va1, pb11, od[1][dt], 0, 0, 0);
        }
        dq0 = __builtin_amdgcn_mfma_f32_16x16x32_bf16(aones, pb00, dq0, 0, 0, 0);
        dq0 = __builtin_amdgcn_mfma_f32_16x16x32_bf16(aones, pb01, dq0, 0, 0, 0);
        dq1 = __builtin_amdgcn_mfma_f32_16x16x32_bf16(aones, pb10, dq1, 0, 0, 0);
        dq1 = __builtin_amdgcn_mfma_f32_16x16x32_bf16(aones, pb11, dq1, 0, 0, 0);

        __syncthreads();   // PV done pair-wide; next iter may overwrite V
    }

    // ---- cross-pair combine (overlays the K region; all K reads done) ----
    float* cf = (float*)lds_s;   // comb: [qh][qt][dt][16][16] floats; dq at 4096
    if (ph == 1) {
#pragma unroll
        for (int qt = 0; qt < 2; ++qt)
#pragma unroll
            for (int dt = 0; dt < 4; ++dt) {
                float* dst = &cf[((((qh * 2 + qt) * 4 + dt) * 16) + quad * 4) * 16 + l15];
#pragma unroll
                for (int r = 0; r < 4; ++r) dst[r * 16] = od[qt][dt][r];
            }
        if (quad == 0) {
            cf[4096 + (qh * 2 + 0) * 16 + l15] = dq0[0];
            cf[4096 + (qh * 2 + 1) * 16 + l15] = dq1[0];
        }
    }
    __syncthreads();
    if (ph == 0) {
#pragma unroll
        for (int qt = 0; qt < 2; ++qt) {
            const float dtot = ((qt == 0) ? dq0[0] : dq1[0])
                             + cf[4096 + (qh * 2 + qt) * 16 + l15];
            const float inv = 1.f / dtot;
            short* outp = attn_b + (size_t)(s0 + qh * 32 + qt * 16 + l15) * CDIM + head * HD;
#pragma unroll
            for (int dt = 0; dt < 4; ++dt) {
                const float* src = &cf[((((qh * 2 + qt) * 4 + dt) * 16) + quad * 4) * 16 + l15];
                short4v o4;
#pragma unroll
                for (int r = 0; r < 4; ++r)
                    o4[r] = f2b((od[qt][dt][r] + src[r * 16]) * inv);
                *(short4v*)(outp + dt * 16 + quad * 4) = o4;
            }
        }
    }
}

// ---------------------------------------------------------------------------
extern "C" void kernel_launch(void* const* d_in, const int* in_sizes, int n_in,
                              void* d_out, int out_size, void* d_ws, size_t ws_size,
                              hipStream_t stream)
{
    const float* x    = (const float*)d_in[0];
    const float* qkvw = (const float*)d_in[1];
    const float* qkvb = (const float*)d_in[2];
    const float* rph  = (const float*)d_in[3];
    const float* rpw  = (const float*)d_in[4];
    const float* pw   = (const float*)d_in[5];
    const float* pb   = (const float*)d_in[6];
    float* out = (float*)d_out;

    // ws layout (shorts), total ~48.8 MB
    const size_t HSD = (size_t)NH * S_TOK * HD;   // 3,145,728
    short* xb     = (short*)d_ws;                 // 4096*768
    short* wt     = xb + (size_t)S_TOK * CDIM;    // 2304*768 (qkv_w^T)
    short* pwt    = wt + (size_t)N3C * CDIM;      // 768*768  (proj_w^T)
    short* Qb     = pwt + (size_t)CDIM * CDIM;
    short* Kb     = Qb + HSD;
    short* Vt     = Kb + HSD;
    short* Relh   = Vt + HSD;
    short* Relw   = Relh + HSD;
    short* attn_b = Relw + HSD;                   // 4096*768

    cast_bf16_kernel<<<S_TOK * CDIM / 4 / 256, 256, 0, stream>>>(x, xb, S_TOK * CDIM / 4);
    transpose_cast_kernel<<<dim3(N3C / 64, CDIM / 64), 256, 0, stream>>>(qkvw, wt, CDIM, N3C);
    transpose_cast_kernel<<<dim3(CDIM / 64, CDIM / 64), 256, 0, stream>>>(pw, pwt, CDIM, CDIM);

    gemm_qkv_mfma<<<dim3(N3C / 128, S_TOK / 128), 256, 0, stream>>>(
        xb, wt, qkvb, Qb, Kb, Vt);
    rel_mfma_kernel<<<dim3(64, NH), 256, 0, stream>>>(Qb, rph, rpw, Relh, Relw);
    flash_kernel<<<dim3(64, NH), 256, 0, stream>>>(Qb, Kb, Vt, Relh, Relw, attn_b);
    gemm_proj_mfma<<<dim3(CDIM / 128, S_TOK / 128), 256, 0, stream>>>(
        attn_b, pwt, pb, out);
}

// Round 4
// 209.607 us; speedup vs baseline: 1.1676x; 1.0696x over previous
//
#include <hip/hip_runtime.h>
#include <hip/hip_bf16.h>

// Problem constants (B=1, H=W=64, C=768, nh=12, hd=64)
#define S_TOK 4096
#define CDIM  768
#define N3C   2304
#define NH    12
#define HD    64

#define LOG2E 1.44269504f

typedef __attribute__((ext_vector_type(8))) short short8;
typedef __attribute__((ext_vector_type(4))) short short4v;
typedef __attribute__((ext_vector_type(4))) float float4v;
typedef __attribute__((ext_vector_type(4))) unsigned uint4v;

__device__ __forceinline__ float b2f(short s) {
    return __uint_as_float(((unsigned)(unsigned short)s) << 16);
}
__device__ __forceinline__ short f2b(float f) {   // round-to-nearest-even
    unsigned u = __float_as_uint(f);
    unsigned r = (u + 0x7FFFu + ((u >> 16) & 1u)) >> 16;
    return (short)r;
}

#if __has_builtin(__builtin_amdgcn_exp2f)
#define EXP2F __builtin_amdgcn_exp2f
#else
#define EXP2F exp2f
#endif

// pack trunc-bf16(a) into low short, trunc-bf16(b) into high short
__device__ __forceinline__ unsigned pack_trunc(float a, float b) {
    return __builtin_amdgcn_perm(__float_as_uint(b), __float_as_uint(a), 0x07060302u);
}

__device__ __forceinline__ short8 u4_to_s8(unsigned a, unsigned b, unsigned c, unsigned d) {
    union { uint4v u; short8 s; } t;
    t.u = (uint4v){a, b, c, d};
    return t.s;
}

// async global->LDS DMA, 16B per lane, dest = ldsbase + lane*16 (linear)
__device__ __forceinline__ void load_lds16(const void* g, void* l) {
    __builtin_amdgcn_global_load_lds(
        (const __attribute__((address_space(1))) unsigned int*)g,
        (__attribute__((address_space(3))) unsigned int*)l, 16, 0, 0);
}

// ---------------------------------------------------------------------------
// Elementwise fp32 -> bf16 cast (4 elems/thread)
// ---------------------------------------------------------------------------
__global__ __launch_bounds__(256) void cast_bf16_kernel(
    const float* __restrict__ in, short* __restrict__ out, int n4)
{
    int i = blockIdx.x * 256 + threadIdx.x;
    if (i >= n4) return;
    float4 v = ((const float4*)in)[i];
    short4v o4 = { f2b(v.x), f2b(v.y), f2b(v.z), f2b(v.w) };
    *(short4v*)&out[(size_t)i * 4] = o4;
}

// ---------------------------------------------------------------------------
// Transpose + cast: in fp32 [R][C] -> out bf16 [C][R]. 64x64 tiles, 256 thr.
// ---------------------------------------------------------------------------
__global__ __launch_bounds__(256) void transpose_cast_kernel(
    const float* __restrict__ in, short* __restrict__ out, int R, int C)
{
    __shared__ float t[64][65];
    const int tid = threadIdx.x;
    const int c0 = blockIdx.x * 64, r0 = blockIdx.y * 64;
    const int li = tid >> 6;      // 0..3
    const int lj = tid & 63;
#pragma unroll
    for (int p = 0; p < 16; ++p) {
        int i = p * 4 + li;
        t[i][lj] = in[(size_t)(r0 + i) * C + c0 + lj];
    }
    __syncthreads();
#pragma unroll
    for (int p = 0; p < 16; ++p) {
        int i = p * 4 + li;
        out[(size_t)(c0 + i) * R + r0 + lj] = f2b(t[lj][i]);
    }
}

// ---------------------------------------------------------------------------
// MFMA GEMM core v2: C[128x128] = A[128xK] @ Bt[128xK]^T
//   Staging via global_load_lds (m97 pattern: +67% over reg-staging on this
//   structure). LDS [128][64] linear dest; 16B slots XOR-swizzled with the
//   inverse swizzle folded into the per-lane GLOBAL source address; frag
//   reads apply the same XOR -> zero bank conflicts (flash-verified mapping).
// ---------------------------------------------------------------------------
#define GEMM_CORE(A_, Bt_)                                                     \
    __shared__ __align__(16) short a_s[128][64];                               \
    __shared__ __align__(16) short b_s[128][64];                               \
    const int tid  = threadIdx.x;                                              \
    const int m0 = blockIdx.y * 128;                                           \
    const int n0 = blockIdx.x * 128;                                           \
    const int lane = tid & 63, w = tid >> 6;                                   \
    const int l15 = lane & 15, quad = lane >> 4;                               \
    const int wr = w >> 1, wc = w & 1;                                         \
    const int roff0 = (quad ^ (l15 & 7)) << 4;                                 \
    const int roff1 = roff0 ^ 64;                                              \
    const int srow0 = w * 8 + (lane >> 3);                                     \
    const int sslot = (lane & 7) ^ ((lane >> 3) & 7);                          \
    const short* ga = A_ + (size_t)(m0 + srow0) * 768 + sslot * 8;             \
    const short* gb = Bt_ + (size_t)(n0 + srow0) * 768 + sslot * 8;            \
    short* la = &a_s[w * 8][0];                                                \
    short* lb = &b_s[w * 8][0];                                                \
    float4v acc[4][4];                                                         \
    _Pragma("unroll")                                                          \
    for (int i = 0; i < 4; ++i)                                                \
        _Pragma("unroll")                                                      \
        for (int j = 0; j < 4; ++j) acc[i][j] = (float4v){0.f,0.f,0.f,0.f};    \
    for (int k0 = 0; k0 < 768; k0 += 64) {                                     \
        __syncthreads();                                                       \
        _Pragma("unroll")                                                      \
        for (int i = 0; i < 4; ++i) {                                          \
            load_lds16(ga + (size_t)i * (32 * 768) + k0, la + i * 32 * 64);    \
            load_lds16(gb + (size_t)i * (32 * 768) + k0, lb + i * 32 * 64);    \
        }                                                                      \
        __syncthreads();                                                       \
        _Pragma("unroll")                                                      \
        for (int kk = 0; kk < 64; kk += 32) {                                  \
            const int roff = kk ? roff1 : roff0;                               \
            short8 af[4], bfr[4];                                              \
            _Pragma("unroll")                                                  \
            for (int i = 0; i < 4; ++i)                                        \
                af[i] = *(const short8*)((const char*)&a_s[wr*64 + i*16 + l15][0] + roff); \
            _Pragma("unroll")                                                  \
            for (int j = 0; j < 4; ++j)                                        \
                bfr[j] = *(const short8*)((const char*)&b_s[wc*64 + j*16 + l15][0] + roff); \
            _Pragma("unroll")                                                  \
            for (int i = 0; i < 4; ++i)                                        \
                _Pragma("unroll")                                              \
                for (int j = 0; j < 4; ++j)                                    \
                    acc[i][j] = __builtin_amdgcn_mfma_f32_16x16x32_bf16(       \
                        af[i], bfr[j], acc[i][j], 0, 0, 0);                    \
        }                                                                      \
    }

// QKV GEMM: writes Qb[head][s][d], Kb[head][s][d], Vt[head][d][s] (bf16)
__global__ __launch_bounds__(256) void gemm_qkv_mfma(
    const short* __restrict__ A, const short* __restrict__ Bt,
    const float* __restrict__ bias,
    short* __restrict__ Qb, short* __restrict__ Kb, short* __restrict__ Vt)
{
    GEMM_CORE(A, Bt)

    const int sec = n0 / CDIM;      // tile fully inside one of q/k/v
    float bj[4];
#pragma unroll
    for (int j = 0; j < 4; ++j) bj[j] = bias[n0 + wc*64 + j*16 + l15];

    if (sec < 2) {
        short* dst = (sec == 0) ? Qb : Kb;
#pragma unroll
        for (int i = 0; i < 4; ++i)
#pragma unroll
            for (int j = 0; j < 4; ++j) {
                const int nn = (n0 + wc*64 + j*16 + l15) % CDIM;
                const int head = nn >> 6, d = nn & 63;
#pragma unroll
                for (int r = 0; r < 4; ++r) {
                    const int s = m0 + wr*64 + i*16 + quad*4 + r;
                    dst[((size_t)head * S_TOK + s) * HD + d] = f2b(acc[i][j][r] + bj[j]);
                }
            }
    } else {
#pragma unroll
        for (int i = 0; i < 4; ++i)
#pragma unroll
            for (int j = 0; j < 4; ++j) {
                const int nn = (n0 + wc*64 + j*16 + l15) % CDIM;
                const int head = nn >> 6, d = nn & 63;
                const int sbase = m0 + wr*64 + i*16 + quad*4;
                short4v v4;
#pragma unroll
                for (int r = 0; r < 4; ++r) v4[r] = f2b(acc[i][j][r] + bj[j]);
                *(short4v*)&Vt[((size_t)head * HD + d) * S_TOK + sbase] = v4;
            }
    }
}

// Proj GEMM: out fp32 [4096][768] = A @ Bt^T + bias
__global__ __launch_bounds__(256) void gemm_proj_mfma(
    const short* __restrict__ A, const short* __restrict__ Bt,
    const float* __restrict__ bias, float* __restrict__ out)
{
    GEMM_CORE(A, Bt)

    float bj[4];
#pragma unroll
    for (int j = 0; j < 4; ++j) bj[j] = bias[n0 + wc*64 + j*16 + l15];

#pragma unroll
    for (int i = 0; i < 4; ++i)
#pragma unroll
        for (int j = 0; j < 4; ++j) {
            const int n = n0 + wc*64 + j*16 + l15;
#pragma unroll
            for (int r = 0; r < 4; ++r) {
                const int s = m0 + wr*64 + i*16 + quad*4 + r;
                out[(size_t)s * CDIM + n] = acc[i][j][r] + bj[j];
            }
        }
}

// ---------------------------------------------------------------------------
// Rel-pos tables via MFMA. One block per (y, head); 64 queries s0=y*64..+63.
// Outputs PRE-SCALED by log2e (flash computes softmax in exp2 domain).
// Relh is stored TRANSPOSED: RelhT[head][ky][s] -> short4v stores here and
// coalesced per-chunk loads in flash (ky == chunk index).
// ---------------------------------------------------------------------------
__global__ __launch_bounds__(256) void rel_mfma_kernel(
    const short* __restrict__ Qb, const float* __restrict__ rph,
    const float* __restrict__ rpw, short* __restrict__ RelhT,
    short* __restrict__ Relw)
{
    __shared__ __align__(16) short q_s [64][72];
    __shared__ __align__(16) short rh_s[64][72];
    __shared__ __align__(16) short rw_s[128][72];

    const int tid  = threadIdx.x;
    const int y    = blockIdx.x;
    const int head = blockIdx.y;
    const int s0   = y * 64;
    const int w = tid >> 6, lane = tid & 63;
    const int l15 = lane & 15, quad = lane >> 4;
    const int srow = tid >> 2;            // 0..63
    const int scol = (tid & 3) << 4;      // 0,16,32,48

    // ---- stage Q (bf16 passthrough) ----
    {
        const uint4* g = (const uint4*)(Qb + ((size_t)head * S_TOK + s0 + srow) * HD + scol);
        *(uint4*)&q_s[srow][scol]     = g[0];
        *(uint4*)&q_s[srow][scol + 8] = g[1];
    }
    // ---- stage rph rows y..y+63 (fp32 -> bf16) ----
    {
        const float* g = rph + (size_t)(y + srow) * HD + scol;
        short tmp[16];
#pragma unroll
        for (int i = 0; i < 16; i += 4) {
            float4 v = *(const float4*)(g + i);
            tmp[i] = f2b(v.x); tmp[i+1] = f2b(v.y); tmp[i+2] = f2b(v.z); tmp[i+3] = f2b(v.w);
        }
        *(short8*)&rh_s[srow][scol]     = *(short8*)&tmp[0];
        *(short8*)&rh_s[srow][scol + 8] = *(short8*)&tmp[8];
    }
    // ---- stage rpw rows 0..127 (row 127 clamped; never consumed) ----
#pragma unroll
    for (int half = 0; half < 2; ++half) {
        const int row = srow + half * 64;
        const int rr  = row > 126 ? 126 : row;
        const float* g = rpw + (size_t)rr * HD + scol;
        short tmp[16];
#pragma unroll
        for (int i = 0; i < 16; i += 4) {
            float4 v = *(const float4*)(g + i);
            tmp[i] = f2b(v.x); tmp[i+1] = f2b(v.y); tmp[i+2] = f2b(v.z); tmp[i+3] = f2b(v.w);
        }
        *(short8*)&rw_s[row][scol]     = *(short8*)&tmp[0];
        *(short8*)&rw_s[row][scol + 8] = *(short8*)&tmp[8];
    }
    __syncthreads();

    const short8 qa0 = *(const short8*)&q_s[w * 16 + l15][quad * 8];
    const short8 qa1 = *(const short8*)&q_s[w * 16 + l15][32 + quad * 8];

    // ---- relh: RH col j = y+jj, ky = 63-jj; transposed short4v stores ----
#pragma unroll
    for (int ct = 0; ct < 4; ++ct) {
        const int jj = ct * 16 + l15;
        short8 b0 = *(const short8*)&rh_s[jj][quad * 8];
        short8 b1 = *(const short8*)&rh_s[jj][32 + quad * 8];
        float4v z = (float4v){0.f, 0.f, 0.f, 0.f};
        z = __builtin_amdgcn_mfma_f32_16x16x32_bf16(qa0, b0, z, 0, 0, 0);
        z = __builtin_amdgcn_mfma_f32_16x16x32_bf16(qa1, b1, z, 0, 0, 0);
        const int ky = 63 - jj;
        short4v o4;
#pragma unroll
        for (int r = 0; r < 4; ++r) o4[r] = f2b(z[r] * LOG2E);
        *(short4v*)&RelhT[((size_t)head * HD + ky) * S_TOK + s0 + w * 16 + quad * 4] = o4;
    }

    // ---- relw: kx = q+63-j, keep 0<=kx<64 ----
#pragma unroll
    for (int ct = 0; ct < 8; ++ct) {
        const int j = ct * 16 + l15;
        short8 b0 = *(const short8*)&rw_s[j][quad * 8];
        short8 b1 = *(const short8*)&rw_s[j][32 + quad * 8];
        float4v z = (float4v){0.f, 0.f, 0.f, 0.f};
        z = __builtin_amdgcn_mfma_f32_16x16x32_bf16(qa0, b0, z, 0, 0, 0);
        z = __builtin_amdgcn_mfma_f32_16x16x32_bf16(qa1, b1, z, 0, 0, 0);
#pragma unroll
        for (int r = 0; r < 4; ++r) {
            const int q  = w * 16 + quad * 4 + r;
            const int kx = q + 63 - j;
            if (kx >= 0 && kx < 64)
                Relw[((size_t)head * S_TOK + s0 + q) * HD + kx] = f2b(z[r] * LOG2E);
        }
    }
}

// ---------------------------------------------------------------------------
// Flash attention v7 = v6 + T5 setprio around PV MFMA cluster + transposed
// Relh (coalesced, prefetched per-chunk loads).
//   Pair-split over key chunks, 256 threads / 4 waves: waves {0,1} (ph=0)
//   process key chunks 0..31, waves {2,3} (ph=1) chunks 32..63; within a pair
//   each wave owns 32 queries. Partials combined through LDS at the end.
//   Staging via global_load_lds (linear dest, pre-swizzled source, swizzled
//   read -> zero bank conflicts). K double-buffered per pair, V single-
//   buffered (2 barriers per chunk-step). Key bit-permutation: LDS row j
//   holds key(j) = (j&3) | ((j>>4)&1)<<2 | ((j>>2)&3)<<3 | (j&32) so S^T
//   tile kt's outputs are the lane's own PV B-frag keys (no P round-trip).
// ---------------------------------------------------------------------------
__global__ __launch_bounds__(256, 3) void flash_kernel(
    const short* __restrict__ Qb, const short* __restrict__ Kb,
    const short* __restrict__ Vt, const short* __restrict__ RelhT,
    const short* __restrict__ Relw, short* __restrict__ attn_b)
{
    // shorts 0..16383: K[pair][buf][64][64]; 16384..24575: V[pair][64][64]
    __shared__ __align__(16) short lds_s[24576];

    const int tid  = threadIdx.x;
    const int head = blockIdx.y;
    const int s0   = blockIdx.x * 64;
    const int w    = tid >> 6, lane = tid & 63;
    const int l15  = lane & 15, quad = lane >> 4;
    const int ph   = w >> 1;          // key-chunk half: chunks ph*32 + t
    const int qh   = w & 1;           // query half: queries qh*32 + ...

    const float C1 = 0.125f * LOG2E;

    // ---- staging lane mapping (linear dest, pre-swizzled source) ----
    const int lj = lane >> 3;             // row within 8-row DMA group
    const int sl = (lane & 7) ^ lj;       // logical 16B slot this lane fetches
    const int kf0 = (lj & 3) + ((lj & 4) << 1) + qh * 32;  // permuted key, ii=0

    const short* pKs = Kb + (size_t)head * S_TOK * HD
                     + (size_t)(ph * 32 * 64 + kf0) * HD + sl * 8;
    const short* pVs = Vt + ((size_t)head * HD + qh * 32 + lj) * S_TOK
                     + ph * 32 * 64 + sl * 8;

    // wave-uniform LDS dest bases
    short* lk0 = &lds_s[(ph * 2 + 0) << 12] + qh * 32 * 64;
    short* lk1 = &lds_s[(ph * 2 + 1) << 12] + qh * 32 * 64;
    short* lv  = &lds_s[16384 + (ph << 12)] + qh * 32 * 64;
    const short* krd0 = &lds_s[(ph * 2 + 0) << 12];
    const short* krd1 = &lds_s[(ph * 2 + 1) << 12];
    const short* vrd  = &lds_s[16384 + (ph << 12)];

    // swizzled read byte-offsets (row&7 == l15&7 for all frag rows)
    const int roff0 = (quad ^ (l15 & 7)) << 4;   // logical slot quad
    const int roff1 = roff0 ^ 64;                // logical slot 4+quad

    // ---- Q B-frags: 2 q-tiles (32 queries per wave) ----
    short8 qb[2][2];
#pragma unroll
    for (int qt = 0; qt < 2; ++qt) {
        const short* qrow = Qb + ((size_t)head * S_TOK + s0 + qh * 32 + qt * 16 + l15) * HD;
        qb[qt][0] = *(const short8*)(qrow + quad * 8);
        qb[qt][1] = *(const short8*)(qrow + 32 + quad * 8);
    }

    // ---- relw invariants: rwv[qt][kt][r], key = kbase(kt) + quad*8 + r ----
    float rwv[2][4][4];
#pragma unroll
    for (int qt = 0; qt < 2; ++qt) {
        const short* rwrow = Relw + ((size_t)head * S_TOK + s0 + qh * 32 + qt * 16 + l15) * HD;
#pragma unroll
        for (int kt = 0; kt < 4; ++kt) {
            const int base = ((kt & 1) << 2) | ((kt >> 1) << 5);
            short4v v = *(const short4v*)(rwrow + base + quad * 8);
#pragma unroll
            for (int r = 0; r < 4; ++r) rwv[qt][kt][r] = b2f(v[r]);
        }
    }

    // RelhT[head][ky][s]: per-chunk coalesced loads (ky == chunk index)
    const short* rhbase = RelhT + (size_t)head * HD * S_TOK + s0 + qh * 32 + l15;
    float rhc0 = b2f(rhbase[(size_t)(ph * 32) * S_TOK]);
    float rhc1 = b2f(rhbase[(size_t)(ph * 32) * S_TOK + 16]);

    // ones A-frag for the denominator
    short8 aones;
#pragma unroll
    for (int j = 0; j < 8; ++j) aones[j] = (short)0x3F80;

    float4v od[2][4];
#pragma unroll
    for (int qt = 0; qt < 2; ++qt)
#pragma unroll
        for (int dt = 0; dt < 4; ++dt) od[qt][dt] = (float4v){0.f, 0.f, 0.f, 0.f};
    float4v dq0 = (float4v){0.f, 0.f, 0.f, 0.f};
    float4v dq1 = (float4v){0.f, 0.f, 0.f, 0.f};

    // ---- prologue: DMA K chunk (ph*32) into buf0 ----
    load_lds16(pKs,        lk0);
    load_lds16(pKs + 1024, lk0 + 8  * 64);
    load_lds16(pKs + 256,  lk0 + 16 * 64);
    load_lds16(pKs + 1280, lk0 + 24 * 64);
    __syncthreads();

    for (int t = 0; t < 32; ++t) {
        const int cur = t & 1;
        const short* krd = cur ? krd1 : krd0;
        short* lkn = cur ? lk0 : lk1;

        // ---- V-DMA current chunk (prev PV separated by loop-end barrier) ----
        load_lds16(pVs,               lv);
        load_lds16(pVs + 8  * S_TOK,  lv + 8  * 64);
        load_lds16(pVs + 16 * S_TOK,  lv + 16 * 64);
        load_lds16(pVs + 24 * S_TOK,  lv + 24 * 64);
        // ---- K-DMA next chunk into the other buffer ----
        if (t < 31) {
            const short* pk = pKs + 4096;
            load_lds16(pk,        lkn);
            load_lds16(pk + 1024, lkn + 8  * 64);
            load_lds16(pk + 256,  lkn + 16 * 64);
            load_lds16(pk + 1280, lkn + 24 * 64);
        }
        pKs += 4096;
        pVs += 64;

        // ---- prefetch next chunk's rh (coalesced 2B loads) ----
        short rhn0, rhn1;
        if (t < 31) {
            rhn0 = rhbase[(size_t)(ph * 32 + t + 1) * S_TOK];
            rhn1 = rhbase[(size_t)(ph * 32 + t + 1) * S_TOK + 16];
        }

        // ---- S-phase: K frags read once, used by both q-tiles ----
        unsigned pkk[2][8];
#pragma unroll
        for (int kt = 0; kt < 4; ++kt) {
            const char* krp = (const char*)(krd + (kt * 16 + l15) * 64);
            const short8 ka0 = *(const short8*)(krp + roff0);
            const short8 ka1 = *(const short8*)(krp + roff1);
            {
                float4v z = (float4v){0.f, 0.f, 0.f, 0.f};
                z = __builtin_amdgcn_mfma_f32_16x16x32_bf16(ka0, qb[0][0], z, 0, 0, 0);
                z = __builtin_amdgcn_mfma_f32_16x16x32_bf16(ka1, qb[0][1], z, 0, 0, 0);
                float p0 = EXP2F(C1 * z[0] + (rhc0 + rwv[0][kt][0]));
                float p1 = EXP2F(C1 * z[1] + (rhc0 + rwv[0][kt][1]));
                float p2 = EXP2F(C1 * z[2] + (rhc0 + rwv[0][kt][2]));
                float p3 = EXP2F(C1 * z[3] + (rhc0 + rwv[0][kt][3]));
                pkk[0][kt * 2]     = pack_trunc(p0, p1);
                pkk[0][kt * 2 + 1] = pack_trunc(p2, p3);
            }
            {
                float4v z = (float4v){0.f, 0.f, 0.f, 0.f};
                z = __builtin_amdgcn_mfma_f32_16x16x32_bf16(ka0, qb[1][0], z, 0, 0, 0);
                z = __builtin_amdgcn_mfma_f32_16x16x32_bf16(ka1, qb[1][1], z, 0, 0, 0);
                float p0 = EXP2F(C1 * z[0] + (rhc1 + rwv[1][kt][0]));
                float p1 = EXP2F(C1 * z[1] + (rhc1 + rwv[1][kt][1]));
                float p2 = EXP2F(C1 * z[2] + (rhc1 + rwv[1][kt][2]));
                float p3 = EXP2F(C1 * z[3] + (rhc1 + rwv[1][kt][3]));
                pkk[1][kt * 2]     = pack_trunc(p0, p1);
                pkk[1][kt * 2 + 1] = pack_trunc(p2, p3);
            }
        }
        const short8 pb00 = u4_to_s8(pkk[0][0], pkk[0][1], pkk[0][2], pkk[0][3]);
        const short8 pb01 = u4_to_s8(pkk[0][4], pkk[0][5], pkk[0][6], pkk[0][7]);
        const short8 pb10 = u4_to_s8(pkk[1][0], pkk[1][1], pkk[1][2], pkk[1][3]);
        const short8 pb11 = u4_to_s8(pkk[1][4], pkk[1][5], pkk[1][6], pkk[1][7]);

        __syncthreads();   // drains vmcnt: V (and next K) landed; K reads done

        // ---- PV: V frags read once, used by both q-tiles (T5 setprio) ----
        __builtin_amdgcn_s_setprio(1);
#pragma unroll
        for (int dt = 0; dt < 4; ++dt) {
            const char* vrp = (const char*)(vrd + (dt * 16 + l15) * 64);
            const short8 va0 = *(const short8*)(vrp + roff0);
            const short8 va1 = *(const short8*)(vrp + roff1);
            od[0][dt] = __builtin_amdgcn_mfma_f32_16x16x32_bf16(va0, pb00, od[0][dt], 0, 0, 0);
            od[0][dt] = __builtin_amdgcn_mfma_f32_16x16x32_bf16(va1, pb01, od[0][dt], 0, 0, 0);
            od[1][dt] = __builtin_amdgcn_mfma_f32_16x16x32_bf16(va0, pb10, od[1][dt], 0, 0, 0);
            od[1][dt] = __builtin_amdgcn_mfma_f32_16x16x32_bf16(va1, pb11, od[1][dt], 0, 0, 0);
        }
        dq0 = __builtin_amdgcn_mfma_f32_16x16x32_bf16(aones, pb00, dq0, 0, 0, 0);
        dq0 = __builtin_amdgcn_mfma_f32_16x16x32_bf16(aones, pb01, dq0, 0, 0, 0);
        dq1 = __builtin_amdgcn_mfma_f32_16x16x32_bf16(aones, pb10, dq1, 0, 0, 0);
        dq1 = __builtin_amdgcn_mfma_f32_16x16x32_bf16(aones, pb11, dq1, 0, 0, 0);
        __builtin_amdgcn_s_setprio(0);

        if (t < 31) {
            rhc0 = b2f(rhn0);
            rhc1 = b2f(rhn1);
        }
        __syncthreads();   // PV done pair-wide; next iter may overwrite V
    }

    // ---- cross-pair combine (overlays the K region; all K reads done) ----
    float* cf = (float*)lds_s;   // comb: [qh][qt][dt][16][16] floats; dq at 4096
    if (ph == 1) {
#pragma unroll
        for (int qt = 0; qt < 2; ++qt)
#pragma unroll
            for (int dt = 0; dt < 4; ++dt) {
                float* dst = &cf[((((qh * 2 + qt) * 4 + dt) * 16) + quad * 4) * 16 + l15];
#pragma unroll
                for (int r = 0; r < 4; ++r) dst[r * 16] = od[qt][dt][r];
            }
        if (quad == 0) {
            cf[4096 + (qh * 2 + 0) * 16 + l15] = dq0[0];
            cf[4096 + (qh * 2 + 1) * 16 + l15] = dq1[0];
        }
    }
    __syncthreads();
    if (ph == 0) {
#pragma unroll
        for (int qt = 0; qt < 2; ++qt) {
            const float dtot = ((qt == 0) ? dq0[0] : dq1[0])
                             + cf[4096 + (qh * 2 + qt) * 16 + l15];
            const float inv = 1.f / dtot;
            short* outp = attn_b + (size_t)(s0 + qh * 32 + qt * 16 + l15) * CDIM + head * HD;
#pragma unroll
            for (int dt = 0; dt < 4; ++dt) {
                const float* src = &cf[((((qh * 2 + qt) * 4 + dt) * 16) + quad * 4) * 16 + l15];
                short4v o4;
#pragma unroll
                for (int r = 0; r < 4; ++r)
                    o4[r] = f2b((od[qt][dt][r] + src[r * 16]) * inv);
                *(short4v*)(outp + dt * 16 + quad * 4) = o4;
            }
        }
    }
}

// ---------------------------------------------------------------------------
extern "C" void kernel_launch(void* const* d_in, const int* in_sizes, int n_in,
                              void* d_out, int out_size, void* d_ws, size_t ws_size,
                              hipStream_t stream)
{
    const float* x    = (const float*)d_in[0];
    const float* qkvw = (const float*)d_in[1];
    const float* qkvb = (const float*)d_in[2];
    const float* rph  = (const float*)d_in[3];
    const float* rpw  = (const float*)d_in[4];
    const float* pw   = (const float*)d_in[5];
    const float* pb   = (const float*)d_in[6];
    float* out = (float*)d_out;

    // ws layout (shorts), total ~48.8 MB
    const size_t HSD = (size_t)NH * S_TOK * HD;   // 3,145,728
    short* xb     = (short*)d_ws;                 // 4096*768
    short* wt     = xb + (size_t)S_TOK * CDIM;    // 2304*768 (qkv_w^T)
    short* pwt    = wt + (size_t)N3C * CDIM;      // 768*768  (proj_w^T)
    short* Qb     = pwt + (size_t)CDIM * CDIM;
    short* Kb     = Qb + HSD;
    short* Vt     = Kb + HSD;
    short* RelhT  = Vt + HSD;                     // [head][ky][s]
    short* Relw   = RelhT + HSD;
    short* attn_b = Relw + HSD;                   // 4096*768

    cast_bf16_kernel<<<S_TOK * CDIM / 4 / 256, 256, 0, stream>>>(x, xb, S_TOK * CDIM / 4);
    transpose_cast_kernel<<<dim3(N3C / 64, CDIM / 64), 256, 0, stream>>>(qkvw, wt, CDIM, N3C);
    transpose_cast_kernel<<<dim3(CDIM / 64, CDIM / 64), 256, 0, stream>>>(pw, pwt, CDIM, CDIM);

    gemm_qkv_mfma<<<dim3(N3C / 128, S_TOK / 128), 256, 0, stream>>>(
        xb, wt, qkvb, Qb, Kb, Vt);
    rel_mfma_kernel<<<dim3(64, NH), 256, 0, stream>>>(Qb, rph, rpw, RelhT, Relw);
    flash_kernel<<<dim3(64, NH), 256, 0, stream>>>(Qb, Kb, Vt, RelhT, Relw, attn_b);
    gemm_proj_mfma<<<dim3(CDIM / 128, S_TOK / 128), 256, 0, stream>>>(
        attn_b, pwt, pb, out);
}